// Round 11
// baseline (180.732 us; speedup 1.0000x reference)
//
#include <hip/hip_runtime.h>
#include <hip/hip_bf16.h>

typedef __attribute__((ext_vector_type(4))) float f32x4;
typedef __attribute__((ext_vector_type(8))) short bf16x8;
typedef unsigned short ushort_t;

#define T_LEN 8192
#define N_REFL 8187              // last valid phase index (phase arrays have 8188 elems)
#define POSTRIDE 66              // u16 per phase row (boundary path only)
#define PH_U16 (80 * POSTRIDE)   // 5280 u16 per phase (boundary path only)
#define N_INT 4032               // interior blocks: 126 tiles * 2 g * 16 b
#define WS_WPK_OFF 262144        // wpk offset in ws (wold occupies first 212,992 B)

__device__ __forceinline__ ushort_t f2bf(float f) {
    union { float f; unsigned u; } a; a.f = f;
    unsigned r = a.u + 0x7FFF + ((a.u >> 16) & 1);
    return (ushort_t)(r >> 16);
}

union bf2u { __hip_bfloat162 h; unsigned u; ushort_t s[2]; };

__device__ __forceinline__ unsigned pack_bf2(float a, float b) {
    bf2u x; x.h = __float22bfloat162_rn(make_float2(a, b));  // v_cvt_pk_bf16_f32
    return x.u;
}
__device__ __forceinline__ float bflo(unsigned u) {
    union { unsigned u; float f; } x; x.u = u << 16; return x.f;
}
__device__ __forceinline__ float bfhi(unsigned u) {
    union { unsigned u; float f; } x; x.u = u & 0xffff0000u; return x.f;
}
__device__ __forceinline__ float qgelu(float d) {
    return __fdividef(d, 1.f + __expf(-1.702f * d));
}
__device__ __forceinline__ float rot_lane(float v, int byteIdx) {
    int r = __builtin_amdgcn_ds_bpermute(byteIdx, __builtin_bit_cast(int, v));
    return __builtin_bit_cast(float, r);
}

// ---------------------------------------------------------------------------
// Part A: wold[tap][o][c] bf16 (boundary kernel).
// Part B: wpk[g][wv][fid][lane][8] bf16 — per-lane MFMA fragment layout so each
//         weight-load instruction reads 1KB CONTIGUOUS.
//         fid = 3j+phase, j=(u,h) pair 0..9; phase 0=A(tap 3u),1=L0(3u+2),2=L1(3u+1).
__global__ void convert_w_kernel(const float* __restrict__ w,
                                 ushort_t* __restrict__ wold,
                                 ushort_t* __restrict__ wpk) {
    int bid = blockIdx.x;
    int tid = threadIdx.x;
    if (bid < 416) {
        int idx = bid * 256 + tid;
        if (idx >= 128 * 64 * 13) return;
        int tap = idx % 13;
        int c   = (idx / 13) & 63;
        int o   = idx / (13 * 64);
        wold[(tap * 128 + o) * 64 + c] = f2bf(w[idx]);
    } else {
        int e0   = (bid - 416) * 256 + tid;      // 0 .. 15359
        int lane = e0 & 63;
        int rest = e0 >> 6;                       // g*120 + wv*30 + fid
        int fid  = rest % 30;
        int wv   = (rest / 30) & 3;
        int g    = rest / 120;
        int j = fid / 3, phase = fid % 3;
        int u = j >> 1, h = j & 1;
        int row = lane & 15, kb = lane >> 4;
        int wo  = g * 64 + wv * 16 + row;
        int tap = 3 * u + ((phase == 0) ? 0 : (phase == 1) ? 2 : 1);
        bool zero = (phase != 0) && (u == 4);
        ushort_t* dst = wpk + (size_t)e0 * 8;
        #pragma unroll
        for (int e = 0; e < 8; ++e) {
            int c = h * 32 + kb * 8 + e;
            float v = zero ? 0.f : w[((size_t)wo * 64 + c) * 13 + tap];
            dst[e] = f2bf(v);
        }
    }
}

// ---------------------------------------------------------------------------
// Interior kernel (tiles 1..126): R9 structure; rolling per-q epilogue frees
// ~20 arch VGPRs so launch_bounds(256,5) fits -> 5 waves/SIMD.
__global__ __launch_bounds__(256, 5)
void fused_int_kernel(const float* __restrict__ x, const ushort_t* __restrict__ wpk,
                      const float* __restrict__ bias, float* __restrict__ out) {
    __shared__ ushort_t xs[88 * 64];    // 11,264 B, XOR-swizzled

    const int bx   = blockIdx.x;
    const int tid  = threadIdx.x;
    const int lane = tid & 63;
    const int wv   = tid >> 6;
    const int row  = lane & 15;
    const int kb   = lane >> 4;

    const int gb   = bx / 126;
    const int tile = 1 + (bx - gb * 126);
    const int g    = gb & 1;
    const int b    = gb >> 1;
    const int t0   = tile * 64;
    const int mbase = t0 - 8;            // in-range 56..8056 for all interior tiles

    // ---- stage x[group ch][mbase..mbase+87] -> xs[s][c^((s&7)<<3)] bf16 ----
    const float* xg = x + ((size_t)b * 128 + (size_t)g * 64) * T_LEN;
    for (int cid = tid; cid < 64 * 22; cid += 256) {
        int c  = cid & 63;
        int s0 = (cid >> 6) * 4;
        float4 v = *(const float4*)(xg + (size_t)c * T_LEN + (mbase + s0));
        unsigned p01 = pack_bf2(v.x, v.y);
        unsigned p23 = pack_bf2(v.z, v.w);
        xs[(s0 + 0) * 64 + (c ^ (((s0 + 0) & 7) << 3))] = (ushort_t)(p01 & 0xffff);
        xs[(s0 + 1) * 64 + (c ^ (((s0 + 1) & 7) << 3))] = (ushort_t)(p01 >> 16);
        xs[(s0 + 2) * 64 + (c ^ (((s0 + 2) & 7) << 3))] = (ushort_t)(p23 & 0xffff);
        xs[(s0 + 3) * 64 + (c ^ (((s0 + 3) & 7) << 3))] = (ushort_t)(p23 >> 16);
    }
    const int wo = g * 64 + wv * 16 + row;
    const float bo = bias[wo];
    // per-lane packed weight base: fragment f lives at wp + f*512 (64 lanes * 8 u16)
    const ushort_t* wp = wpk + (((size_t)(g * 4 + wv)) * 30 * 64 + lane) * 8;
    __syncthreads();

    f32x4 accA[5], accL0[5], accL1[5];
    #pragma unroll
    for (int q = 0; q < 5; ++q) {
        accA[q]  = (f32x4){0.f, 0.f, 0.f, 0.f};
        accL0[q] = (f32x4){0.f, 0.f, 0.f, 0.f};
        accL1[q] = (f32x4){0.f, 0.f, 0.f, 0.f};
    }

    #pragma unroll
    for (int j = 0; j < 10; ++j) {
        const int u = j >> 1, h = j & 1;
        bf16x8 wf0 = *(const bf16x8*)(wp + (3 * j + 0) * 512);
        bf16x8 wf1 = {}, wf2 = {};
        if (u < 4) {
            wf1 = *(const bf16x8*)(wp + (3 * j + 1) * 512);
            wf2 = *(const bf16x8*)(wp + (3 * j + 2) * 512);
        }
        #pragma unroll
        for (int q = 0; q < 5; ++q) {
            int s = 16 * q + row + u;
            const bf16x8 xa = *(const bf16x8*)(xs + s * 64 + ((h * 32 + kb * 8) ^ ((s & 7) << 3)));
            accA[q] = __builtin_amdgcn_mfma_f32_16x16x32_bf16(xa, wf0, accA[q], 0, 0, 0);
            if (u < 4) {
                accL0[q] = __builtin_amdgcn_mfma_f32_16x16x32_bf16(xa, wf1, accL0[q], 0, 0, 0);
                accL1[q] = __builtin_amdgcn_mfma_f32_16x16x32_bf16(xa, wf2, accL1[q], 0, 0, 0);
            }
        }
    }

    // ---- rolling in-register epilogue: 12 live neighbor values instead of 32 ----
    const int upIdx = ((lane + 16) & 63) << 2;
    const int dnIdx = ((lane + 48) & 63) << 2;
    const bool kbLT3 = (kb < 3);
    const bool kbGT0 = (kb > 0);
    const float c7bo = 7.f * bo;
    float* outBase = out + ((size_t)(b * 128 + wo)) * T_LEN + (t0 - 6 + 4 * kb);

    // prologue: current-q neighbor values for q=0
    float cu0 = rot_lane(accA[0][0], upIdx);
    float cu1 = rot_lane(accA[0][1], upIdx);
    float clu = rot_lane(accL0[0][0], upIdx);
    float clv = rot_lane(accL1[0][0], upIdx);
    float cd2 = rot_lane(accA[0][2], dnIdx);
    float cd3 = rot_lane(accA[0][3], dnIdx);
    float pd2 = 0.f, pd3 = 0.f;          // d2m[q-1], d3m[q-1] (q=0 -> 0)

    #pragma unroll
    for (int q = 0; q < 5; ++q) {
        float nu0, nu1, nlu, nlv;
        if (q < 4) {
            nu0 = rot_lane(accA[q + 1][0], upIdx);
            nu1 = rot_lane(accA[q + 1][1], upIdx);
            nlu = rot_lane(accL0[q + 1][0], upIdx);
            nlv = rot_lane(accL1[q + 1][0], upIdx);
        } else {
            nu0 = 0.f; nu1 = 0.f; nlu = 0.f; nlv = 0.f;
        }

        #pragma unroll
        for (int r = 0; r < 4; ++r) {
            float A0 = accA[q][r];
            float Ap1 = (r < 3) ? accA[q][r + 1] : (kbLT3 ? cu0 : nu0);
            float Ap2 = (r == 0) ? accA[q][2]
                      : (r == 1) ? accA[q][3]
                      : (r == 2) ? (kbLT3 ? cu0 : nu0)
                                 : (kbLT3 ? cu1 : nu1);
            float Am1 = (r > 0) ? accA[q][r - 1] : (kbGT0 ? cd3 : pd3);
            float Am2 = (r == 2) ? accA[q][0]
                      : (r == 3) ? accA[q][1]
                      : (r == 1) ? (kbGT0 ? cd3 : pd3)
                                 : (kbGT0 ? cd2 : pd2);
            float L0a = accL0[q][r];
            float L0b = (r < 3) ? accL0[q][r + 1] : (kbLT3 ? clu : nlu);
            float L1a = accL1[q][r];
            float L1b = (r < 3) ? accL1[q][r + 1] : (kbLT3 ? clv : nlv);

            float um = fmaxf(fmaxf(fmaxf(Am2, Am1), A0), fmaxf(Ap1, Ap2));
            float res = 2.f * A0 + um + c7bo + (L0b + L0a) + (L1b + L1a)
                      + qgelu(L0b - L0a) + qgelu(L1b - L1a);

            bool ok = true;
            if (q == 0) ok = (4 * kb + r) >= 6;
            if (q == 4) ok = (4 * kb + r) <= 5;
            if (ok) outBase[16 * q + r] = res;
        }

        // roll the window
        pd2 = cd2; pd3 = cd3;
        if (q < 4) {
            cd2 = rot_lane(accA[q + 1][2], dnIdx);
            cd3 = rot_lane(accA[q + 1][3], dnIdx);
            cu0 = nu0; cu1 = nu1; clu = nlu; clv = nlv;
        }
    }
}

// ---------------------------------------------------------------------------
// Boundary kernel (tiles 0 and 127, 64 blocks): proven R3 LDS-phase path.
__global__ __launch_bounds__(256, 4)
void fused_bnd_kernel(const float* __restrict__ x, const ushort_t* __restrict__ wbf,
                      const float* __restrict__ bias, float* __restrict__ out) {
    __shared__ ushort_t smem[3 * PH_U16];   // 31,680 B
    ushort_t* xs = smem;

    const int idx  = blockIdx.x;
    const int tid  = threadIdx.x;
    const int lane = tid & 63;
    const int wv   = tid >> 6;
    const int row  = lane & 15;
    const int kb   = lane >> 4;

    const int tile = (idx & 1) ? 127 : 0;
    const int g    = (idx >> 1) & 1;
    const int b    = idx >> 2;
    const int t0    = tile * 64;
    const int mbase = t0 - 8;

    const float* xg = x + ((size_t)b * 128 + (size_t)g * 64) * T_LEN;
    for (int cid = tid; cid < 64 * 22; cid += 256) {
        int c  = cid & 63;
        int s0 = (cid >> 6) * 4;
        int m0 = mbase + s0;
        const float* src = xg + (size_t)c * T_LEN + m0;
        float v0, v1, v2, v3;
        if (m0 >= 0 && m0 + 3 < T_LEN) {
            float4 v = *(const float4*)src;
            v0 = v.x; v1 = v.y; v2 = v.z; v3 = v.w;
        } else {
            v0 = ((unsigned)(m0 + 0) < (unsigned)T_LEN) ? src[0] : 0.f;
            v1 = ((unsigned)(m0 + 1) < (unsigned)T_LEN) ? src[1] : 0.f;
            v2 = ((unsigned)(m0 + 2) < (unsigned)T_LEN) ? src[2] : 0.f;
            v3 = ((unsigned)(m0 + 3) < (unsigned)T_LEN) ? src[3] : 0.f;
        }
        unsigned p01 = pack_bf2(v0, v1);
        unsigned p23 = pack_bf2(v2, v3);
        xs[(s0 + 0) * 64 + (c ^ (((s0 + 0) & 7) << 3))] = (ushort_t)(p01 & 0xffff);
        xs[(s0 + 1) * 64 + (c ^ (((s0 + 1) & 7) << 3))] = (ushort_t)(p01 >> 16);
        xs[(s0 + 2) * 64 + (c ^ (((s0 + 2) & 7) << 3))] = (ushort_t)(p23 & 0xffff);
        xs[(s0 + 3) * 64 + (c ^ (((s0 + 3) & 7) << 3))] = (ushort_t)(p23 >> 16);
    }
    __syncthreads();

    f32x4 accA[5], accL0[5], accL1[5];
    #pragma unroll
    for (int q = 0; q < 5; ++q) {
        accA[q]  = (f32x4){0.f, 0.f, 0.f, 0.f};
        accL0[q] = (f32x4){0.f, 0.f, 0.f, 0.f};
        accL1[q] = (f32x4){0.f, 0.f, 0.f, 0.f};
    }
    const int wo = g * 64 + wv * 16 + row;

    #pragma unroll
    for (int u = 0; u < 5; ++u) {
        #pragma unroll
        for (int h = 0; h < 2; ++h) {
            bf16x8 wf0 = *(const bf16x8*)(wbf + ((3 * u + 0) * 128 + wo) * 64 + h * 32 + kb * 8);
            bf16x8 wf1 = {}, wf2 = {};
            if (u < 4) {
                wf1 = *(const bf16x8*)(wbf + ((3 * u + 2) * 128 + wo) * 64 + h * 32 + kb * 8);
                wf2 = *(const bf16x8*)(wbf + ((3 * u + 1) * 128 + wo) * 64 + h * 32 + kb * 8);
            }
            #pragma unroll
            for (int q = 0; q < 5; ++q) {
                int s = 16 * q + row + u;
                const bf16x8 xa = *(const bf16x8*)(xs + s * 64 + ((h * 32 + kb * 8) ^ ((s & 7) << 3)));
                accA[q] = __builtin_amdgcn_mfma_f32_16x16x32_bf16(xa, wf0, accA[q], 0, 0, 0);
                if (u < 4) {
                    accL0[q] = __builtin_amdgcn_mfma_f32_16x16x32_bf16(xa, wf1, accL0[q], 0, 0, 0);
                    accL1[q] = __builtin_amdgcn_mfma_f32_16x16x32_bf16(xa, wf2, accL1[q], 0, 0, 0);
                }
            }
        }
    }
    const float bo = bias[wo];
    __syncthreads();

    #pragma unroll
    for (int q = 0; q < 5; ++q) {
        #pragma unroll
        for (int p = 0; p < 3; ++p) {
            const f32x4& a = (p == 0) ? accA[q] : (p == 1) ? accL0[q] : accL1[q];
            unsigned pa = pack_bf2(a[0] + bo, a[1] + bo);
            unsigned pb = pack_bf2(a[2] + bo, a[3] + bo);
            int base = p * PH_U16 + (16 * q + kb * 4) * POSTRIDE + wv * 16 + row;
            smem[base + 0 * POSTRIDE] = (ushort_t)(pa & 0xffff);
            smem[base + 1 * POSTRIDE] = (ushort_t)(pa >> 16);
            smem[base + 2 * POSTRIDE] = (ushort_t)(pb & 0xffff);
            smem[base + 3 * POSTRIDE] = (ushort_t)(pb >> 16);
        }
    }
    __syncthreads();

    const int tl = tid & 63;
    const int wq = tid >> 6;
    const int t  = t0 + tl;
    const ushort_t* phA  = smem;
    const ushort_t* phL0 = smem + PH_U16;
    const ushort_t* phL1 = smem + 2 * PH_U16;
    float* outp = out + ((size_t)b * 128 + (size_t)g * 64) * T_LEN + t;

    int  s5[5];
    bool in5[5];
    #pragma unroll
    for (int dt = 0; dt < 5; ++dt) {
        int tp = t + dt - 2;
        in5[dt] = ((unsigned)tp < (unsigned)T_LEN);
        int ix = tp - 2;
        ix = (ix < 0) ? -ix : ix;
        ix = (ix > N_REFL) ? (2 * N_REFL - ix) : ix;
        s5[dt] = ix - mbase;
    }
    const int sC = s5[2];
    for (int i = 0; i < 8; ++i) {
        int o = 2 * wq + 8 * i;
        unsigned av[5];
        #pragma unroll
        for (int dt = 0; dt < 5; ++dt)
            av[dt] = *(const unsigned*)(phA + s5[dt] * POSTRIDE + o);
        unsigned l0a = *(const unsigned*)(phL0 + (sC    ) * POSTRIDE + o);
        unsigned l0b = *(const unsigned*)(phL0 + (sC + 1) * POSTRIDE + o);
        unsigned l1a = *(const unsigned*)(phL1 + (sC    ) * POSTRIDE + o);
        unsigned l1b = *(const unsigned*)(phL1 + (sC + 1) * POSTRIDE + o);

        float xm_l = bflo(av[2]), xm_h = bfhi(av[2]);
        float um_l = -1e30f, um_h = -1e30f;
        #pragma unroll
        for (int dt = 0; dt < 5; ++dt) {
            um_l = fmaxf(um_l, in5[dt] ? bflo(av[dt]) : 0.f);
            um_h = fmaxf(um_h, in5[dt] ? bfhi(av[dt]) : 0.f);
        }
        float l0al = bflo(l0a), l0bl = bflo(l0b), l1al = bflo(l1a), l1bl = bflo(l1b);
        float l0ah = bfhi(l0a), l0bh = bfhi(l0b), l1ah = bfhi(l1a), l1bh = bfhi(l1b);

        float rl = 2.f * xm_l + um_l + (l0bl + l0al) + qgelu(l0bl - l0al)
                                     + (l1bl + l1al) + qgelu(l1bl - l1al);
        float rh = 2.f * xm_h + um_h + (l0bh + l0ah) + qgelu(l0bh - l0ah)
                                     + (l1bh + l1ah) + qgelu(l1bh - l1ah);
        outp[(size_t)(o    ) * T_LEN] = rl;
        outp[(size_t)(o + 1) * T_LEN] = rh;
    }
}

extern "C" void kernel_launch(void* const* d_in, const int* in_sizes, int n_in,
                              void* d_out, int out_size, void* d_ws, size_t ws_size,
                              hipStream_t stream) {
    const float* x    = (const float*)d_in[0];
    const float* w    = (const float*)d_in[1];
    const float* bias = (const float*)d_in[2];
    float* out        = (float*)d_out;
    ushort_t* wold    = (ushort_t*)d_ws;                         // 212,992 B
    ushort_t* wpk     = (ushort_t*)((char*)d_ws + WS_WPK_OFF);   // 245,760 B

    hipLaunchKernelGGL(convert_w_kernel, dim3(416 + 60), dim3(256), 0, stream,
                       w, wold, wpk);
    hipLaunchKernelGGL(fused_int_kernel, dim3(N_INT), dim3(256), 0, stream,
                       x, wpk, bias, out);
    hipLaunchKernelGGL(fused_bnd_kernel, dim3(64), dim3(256), 0, stream,
                       x, wold, bias, out);
}

// Round 12
// 85.096 us; speedup vs baseline: 2.1238x; 2.1238x over previous
//
#include <hip/hip_runtime.h>
#include <hip/hip_bf16.h>

typedef __attribute__((ext_vector_type(4))) float f32x4;
typedef __attribute__((ext_vector_type(8))) short bf16x8;
typedef unsigned short ushort_t;

#define T_LEN 8192
#define N_REFL 8187              // last valid phase index (phase arrays have 8188 elems)
#define POSTRIDE 66              // u16 per phase row (boundary path only)
#define PH_U16 (80 * POSTRIDE)   // 5280 u16 per phase (boundary path only)
#define N_INT 4032               // interior blocks: 126 tiles * 2 g * 16 b
#define WS_WPK_OFF 262144        // wpk offset in ws (wold occupies first 212,992 B)

__device__ __forceinline__ ushort_t f2bf(float f) {
    union { float f; unsigned u; } a; a.f = f;
    unsigned r = a.u + 0x7FFF + ((a.u >> 16) & 1);
    return (ushort_t)(r >> 16);
}

union bf2u { __hip_bfloat162 h; unsigned u; ushort_t s[2]; };

__device__ __forceinline__ unsigned pack_bf2(float a, float b) {
    bf2u x; x.h = __float22bfloat162_rn(make_float2(a, b));  // v_cvt_pk_bf16_f32
    return x.u;
}
__device__ __forceinline__ float bflo(unsigned u) {
    union { unsigned u; float f; } x; x.u = u << 16; return x.f;
}
__device__ __forceinline__ float bfhi(unsigned u) {
    union { unsigned u; float f; } x; x.u = u & 0xffff0000u; return x.f;
}
// quick_gelu(d) = d / (1 + 2^(-2.4553418 d))  (exp2 form: one fewer v_mul)
__device__ __forceinline__ float qgelu(float d) {
    return __fdividef(d, 1.f + exp2f(-2.4553418f * d));
}
__device__ __forceinline__ float rot_lane(float v, int byteIdx) {
    int r = __builtin_amdgcn_ds_bpermute(byteIdx, __builtin_bit_cast(int, v));
    return __builtin_bit_cast(float, r);
}

// ---------------------------------------------------------------------------
// Part A: wold[tap][o][c] bf16 (boundary kernel).
// Part B: wpk[g][wv][fid][lane][8] bf16 — per-lane MFMA fragment layout so each
//         weight-load instruction reads 1KB CONTIGUOUS.
//         fid = 3j+phase, j=(u,h) pair 0..9; phase 0=A(tap 3u),1=L0(3u+2),2=L1(3u+1).
__global__ void convert_w_kernel(const float* __restrict__ w,
                                 ushort_t* __restrict__ wold,
                                 ushort_t* __restrict__ wpk) {
    int bid = blockIdx.x;
    int tid = threadIdx.x;
    if (bid < 416) {
        int idx = bid * 256 + tid;
        if (idx >= 128 * 64 * 13) return;
        int tap = idx % 13;
        int c   = (idx / 13) & 63;
        int o   = idx / (13 * 64);
        wold[(tap * 128 + o) * 64 + c] = f2bf(w[idx]);
    } else {
        int e0   = (bid - 416) * 256 + tid;      // 0 .. 15359
        int lane = e0 & 63;
        int rest = e0 >> 6;                       // g*120 + wv*30 + fid
        int fid  = rest % 30;
        int wv   = (rest / 30) & 3;
        int g    = rest / 120;
        int j = fid / 3, phase = fid % 3;
        int u = j >> 1, h = j & 1;
        int row = lane & 15, kb = lane >> 4;
        int wo  = g * 64 + wv * 16 + row;
        int tap = 3 * u + ((phase == 0) ? 0 : (phase == 1) ? 2 : 1);
        bool zero = (phase != 0) && (u == 4);
        ushort_t* dst = wpk + (size_t)e0 * 8;
        #pragma unroll
        for (int e = 0; e < 8; ++e) {
            int c = h * 32 + kb * 8 + e;
            float v = zero ? 0.f : w[((size_t)wo * 64 + c) * 13 + tap];
            dst[e] = f2bf(v);
        }
    }
}

// ---------------------------------------------------------------------------
// Interior kernel (tiles 1..126): R9 structure; stage reads re-mapped so 4 lanes
// cover 64B contiguous of one channel (halves stage cache-line transactions).
__global__ __launch_bounds__(256, 4)
void fused_int_kernel(const float* __restrict__ x, const ushort_t* __restrict__ wpk,
                      const float* __restrict__ bias, float* __restrict__ out) {
    __shared__ ushort_t xs[88 * 64];    // 11,264 B, XOR-swizzled

    const int bx   = blockIdx.x;
    const int tid  = threadIdx.x;
    const int lane = tid & 63;
    const int wv   = tid >> 6;
    const int row  = lane & 15;
    const int kb   = lane >> 4;

    const int gb   = bx / 126;
    const int tile = 1 + (bx - gb * 126);
    const int g    = gb & 1;
    const int b    = gb >> 1;
    const int t0   = tile * 64;
    const int mbase = t0 - 8;            // in-range 56..8056 for all interior tiles

    // ---- stage x[group ch][mbase..mbase+87] -> xs[s][c^((s&7)<<3)] bf16 ----
    // Coalesced mapping: consecutive 4 lanes read 64B contiguous of one channel.
    const float* xg = x + ((size_t)b * 128 + (size_t)g * 64) * T_LEN;
    #pragma unroll
    for (int it = 0; it < 5; ++it) {
        int idx = 256 * it + tid;
        int jj  = idx & 3;
        int c   = (idx >> 2) & 63;
        int s0  = 16 * it + 4 * jj;      // rows 0..79
        float4 v = *(const float4*)(xg + (size_t)c * T_LEN + (mbase + s0));
        unsigned p01 = pack_bf2(v.x, v.y);
        unsigned p23 = pack_bf2(v.z, v.w);
        xs[(s0 + 0) * 64 + (c ^ (((s0 + 0) & 7) << 3))] = (ushort_t)(p01 & 0xffff);
        xs[(s0 + 1) * 64 + (c ^ (((s0 + 1) & 7) << 3))] = (ushort_t)(p01 >> 16);
        xs[(s0 + 2) * 64 + (c ^ (((s0 + 2) & 7) << 3))] = (ushort_t)(p23 & 0xffff);
        xs[(s0 + 3) * 64 + (c ^ (((s0 + 3) & 7) << 3))] = (ushort_t)(p23 >> 16);
    }
    if (tid < 128) {                      // tail rows 80..87
        int c  = tid >> 1;
        int s0 = 80 + 4 * (tid & 1);
        float4 v = *(const float4*)(xg + (size_t)c * T_LEN + (mbase + s0));
        unsigned p01 = pack_bf2(v.x, v.y);
        unsigned p23 = pack_bf2(v.z, v.w);
        xs[(s0 + 0) * 64 + (c ^ (((s0 + 0) & 7) << 3))] = (ushort_t)(p01 & 0xffff);
        xs[(s0 + 1) * 64 + (c ^ (((s0 + 1) & 7) << 3))] = (ushort_t)(p01 >> 16);
        xs[(s0 + 2) * 64 + (c ^ (((s0 + 2) & 7) << 3))] = (ushort_t)(p23 & 0xffff);
        xs[(s0 + 3) * 64 + (c ^ (((s0 + 3) & 7) << 3))] = (ushort_t)(p23 >> 16);
    }
    const int wo = g * 64 + wv * 16 + row;
    const float bo = bias[wo];
    // per-lane packed weight base: fragment f lives at wp + f*512 (64 lanes * 8 u16)
    const ushort_t* wp = wpk + (((size_t)(g * 4 + wv)) * 30 * 64 + lane) * 8;
    __syncthreads();

    f32x4 accA[5], accL0[5], accL1[5];
    #pragma unroll
    for (int q = 0; q < 5; ++q) {
        accA[q]  = (f32x4){0.f, 0.f, 0.f, 0.f};
        accL0[q] = (f32x4){0.f, 0.f, 0.f, 0.f};
        accL1[q] = (f32x4){0.f, 0.f, 0.f, 0.f};
    }

    #pragma unroll
    for (int j = 0; j < 10; ++j) {
        const int u = j >> 1, h = j & 1;
        bf16x8 wf0 = *(const bf16x8*)(wp + (3 * j + 0) * 512);
        bf16x8 wf1 = {}, wf2 = {};
        if (u < 4) {
            wf1 = *(const bf16x8*)(wp + (3 * j + 1) * 512);
            wf2 = *(const bf16x8*)(wp + (3 * j + 2) * 512);
        }
        #pragma unroll
        for (int q = 0; q < 5; ++q) {
            int s = 16 * q + row + u;
            const bf16x8 xa = *(const bf16x8*)(xs + s * 64 + ((h * 32 + kb * 8) ^ ((s & 7) << 3)));
            accA[q] = __builtin_amdgcn_mfma_f32_16x16x32_bf16(xa, wf0, accA[q], 0, 0, 0);
            if (u < 4) {
                accL0[q] = __builtin_amdgcn_mfma_f32_16x16x32_bf16(xa, wf1, accL0[q], 0, 0, 0);
                accL1[q] = __builtin_amdgcn_mfma_f32_16x16x32_bf16(xa, wf2, accL1[q], 0, 0, 0);
            }
        }
    }

    // ---- R9 in-register epilogue (verbatim) ----
    const int upIdx = ((lane + 16) & 63) << 2;
    const int dnIdx = ((lane + 48) & 63) << 2;

    float u0[6], u1[6], d2m[5], d3m[5], lu[6], lv[6];
    #pragma unroll
    for (int q = 0; q < 5; ++q) {
        u0[q]  = rot_lane(accA[q][0], upIdx);
        u1[q]  = rot_lane(accA[q][1], upIdx);
        d2m[q] = rot_lane(accA[q][2], dnIdx);
        d3m[q] = rot_lane(accA[q][3], dnIdx);
        lu[q]  = rot_lane(accL0[q][0], upIdx);
        lv[q]  = rot_lane(accL1[q][0], upIdx);
    }
    u0[5] = 0.f; u1[5] = 0.f; lu[5] = 0.f; lv[5] = 0.f;

    const bool kbLT3 = (kb < 3);
    const bool kbGT0 = (kb > 0);
    const float c7bo = 7.f * bo;
    float* outBase = out + ((size_t)(b * 128 + wo)) * T_LEN + (t0 - 6 + 4 * kb);

    #pragma unroll
    for (int q = 0; q < 5; ++q) {
        #pragma unroll
        for (int r = 0; r < 4; ++r) {
            float A0 = accA[q][r];
            float Ap1 = (r < 3) ? accA[q][r + 1] : (kbLT3 ? u0[q] : u0[q + 1]);
            float Ap2 = (r == 0) ? accA[q][2]
                      : (r == 1) ? accA[q][3]
                      : (r == 2) ? (kbLT3 ? u0[q] : u0[q + 1])
                                 : (kbLT3 ? u1[q] : u1[q + 1]);
            float Am1 = (r > 0) ? accA[q][r - 1]
                                : (kbGT0 ? d3m[q] : (q > 0 ? d3m[q - 1] : 0.f));
            float Am2 = (r == 2) ? accA[q][0]
                      : (r == 3) ? accA[q][1]
                      : (r == 1) ? (kbGT0 ? d3m[q] : (q > 0 ? d3m[q - 1] : 0.f))
                                 : (kbGT0 ? d2m[q] : (q > 0 ? d2m[q - 1] : 0.f));
            float L0a = accL0[q][r];
            float L0b = (r < 3) ? accL0[q][r + 1] : (kbLT3 ? lu[q] : lu[q + 1]);
            float L1a = accL1[q][r];
            float L1b = (r < 3) ? accL1[q][r + 1] : (kbLT3 ? lv[q] : lv[q + 1]);

            float um = fmaxf(fmaxf(fmaxf(Am2, Am1), A0), fmaxf(Ap1, Ap2));
            float res = 2.f * A0 + um + c7bo + (L0b + L0a) + (L1b + L1a)
                      + qgelu(L0b - L0a) + qgelu(L1b - L1a);

            bool ok = true;
            if (q == 0) ok = (4 * kb + r) >= 6;
            if (q == 4) ok = (4 * kb + r) <= 5;
            if (ok) outBase[16 * q + r] = res;
        }
    }
}

// ---------------------------------------------------------------------------
// Boundary kernel (tiles 0 and 127, 64 blocks): proven R3 LDS-phase path.
__global__ __launch_bounds__(256, 4)
void fused_bnd_kernel(const float* __restrict__ x, const ushort_t* __restrict__ wbf,
                      const float* __restrict__ bias, float* __restrict__ out) {
    __shared__ ushort_t smem[3 * PH_U16];   // 31,680 B
    ushort_t* xs = smem;

    const int idx  = blockIdx.x;
    const int tid  = threadIdx.x;
    const int lane = tid & 63;
    const int wv   = tid >> 6;
    const int row  = lane & 15;
    const int kb   = lane >> 4;

    const int tile = (idx & 1) ? 127 : 0;
    const int g    = (idx >> 1) & 1;
    const int b    = idx >> 2;
    const int t0    = tile * 64;
    const int mbase = t0 - 8;

    const float* xg = x + ((size_t)b * 128 + (size_t)g * 64) * T_LEN;
    for (int cid = tid; cid < 64 * 22; cid += 256) {
        int c  = cid & 63;
        int s0 = (cid >> 6) * 4;
        int m0 = mbase + s0;
        const float* src = xg + (size_t)c * T_LEN + m0;
        float v0, v1, v2, v3;
        if (m0 >= 0 && m0 + 3 < T_LEN) {
            float4 v = *(const float4*)src;
            v0 = v.x; v1 = v.y; v2 = v.z; v3 = v.w;
        } else {
            v0 = ((unsigned)(m0 + 0) < (unsigned)T_LEN) ? src[0] : 0.f;
            v1 = ((unsigned)(m0 + 1) < (unsigned)T_LEN) ? src[1] : 0.f;
            v2 = ((unsigned)(m0 + 2) < (unsigned)T_LEN) ? src[2] : 0.f;
            v3 = ((unsigned)(m0 + 3) < (unsigned)T_LEN) ? src[3] : 0.f;
        }
        unsigned p01 = pack_bf2(v0, v1);
        unsigned p23 = pack_bf2(v2, v3);
        xs[(s0 + 0) * 64 + (c ^ (((s0 + 0) & 7) << 3))] = (ushort_t)(p01 & 0xffff);
        xs[(s0 + 1) * 64 + (c ^ (((s0 + 1) & 7) << 3))] = (ushort_t)(p01 >> 16);
        xs[(s0 + 2) * 64 + (c ^ (((s0 + 2) & 7) << 3))] = (ushort_t)(p23 & 0xffff);
        xs[(s0 + 3) * 64 + (c ^ (((s0 + 3) & 7) << 3))] = (ushort_t)(p23 >> 16);
    }
    __syncthreads();

    f32x4 accA[5], accL0[5], accL1[5];
    #pragma unroll
    for (int q = 0; q < 5; ++q) {
        accA[q]  = (f32x4){0.f, 0.f, 0.f, 0.f};
        accL0[q] = (f32x4){0.f, 0.f, 0.f, 0.f};
        accL1[q] = (f32x4){0.f, 0.f, 0.f, 0.f};
    }
    const int wo = g * 64 + wv * 16 + row;

    #pragma unroll
    for (int u = 0; u < 5; ++u) {
        #pragma unroll
        for (int h = 0; h < 2; ++h) {
            bf16x8 wf0 = *(const bf16x8*)(wbf + ((3 * u + 0) * 128 + wo) * 64 + h * 32 + kb * 8);
            bf16x8 wf1 = {}, wf2 = {};
            if (u < 4) {
                wf1 = *(const bf16x8*)(wbf + ((3 * u + 2) * 128 + wo) * 64 + h * 32 + kb * 8);
                wf2 = *(const bf16x8*)(wbf + ((3 * u + 1) * 128 + wo) * 64 + h * 32 + kb * 8);
            }
            #pragma unroll
            for (int q = 0; q < 5; ++q) {
                int s = 16 * q + row + u;
                const bf16x8 xa = *(const bf16x8*)(xs + s * 64 + ((h * 32 + kb * 8) ^ ((s & 7) << 3)));
                accA[q] = __builtin_amdgcn_mfma_f32_16x16x32_bf16(xa, wf0, accA[q], 0, 0, 0);
                if (u < 4) {
                    accL0[q] = __builtin_amdgcn_mfma_f32_16x16x32_bf16(xa, wf1, accL0[q], 0, 0, 0);
                    accL1[q] = __builtin_amdgcn_mfma_f32_16x16x32_bf16(xa, wf2, accL1[q], 0, 0, 0);
                }
            }
        }
    }
    const float bo = bias[wo];
    __syncthreads();

    #pragma unroll
    for (int q = 0; q < 5; ++q) {
        #pragma unroll
        for (int p = 0; p < 3; ++p) {
            const f32x4& a = (p == 0) ? accA[q] : (p == 1) ? accL0[q] : accL1[q];
            unsigned pa = pack_bf2(a[0] + bo, a[1] + bo);
            unsigned pb = pack_bf2(a[2] + bo, a[3] + bo);
            int base = p * PH_U16 + (16 * q + kb * 4) * POSTRIDE + wv * 16 + row;
            smem[base + 0 * POSTRIDE] = (ushort_t)(pa & 0xffff);
            smem[base + 1 * POSTRIDE] = (ushort_t)(pa >> 16);
            smem[base + 2 * POSTRIDE] = (ushort_t)(pb & 0xffff);
            smem[base + 3 * POSTRIDE] = (ushort_t)(pb >> 16);
        }
    }
    __syncthreads();

    const int tl = tid & 63;
    const int wq = tid >> 6;
    const int t  = t0 + tl;
    const ushort_t* phA  = smem;
    const ushort_t* phL0 = smem + PH_U16;
    const ushort_t* phL1 = smem + 2 * PH_U16;
    float* outp = out + ((size_t)b * 128 + (size_t)g * 64) * T_LEN + t;

    int  s5[5];
    bool in5[5];
    #pragma unroll
    for (int dt = 0; dt < 5; ++dt) {
        int tp = t + dt - 2;
        in5[dt] = ((unsigned)tp < (unsigned)T_LEN);
        int ix = tp - 2;
        ix = (ix < 0) ? -ix : ix;
        ix = (ix > N_REFL) ? (2 * N_REFL - ix) : ix;
        s5[dt] = ix - mbase;
    }
    const int sC = s5[2];
    for (int i = 0; i < 8; ++i) {
        int o = 2 * wq + 8 * i;
        unsigned av[5];
        #pragma unroll
        for (int dt = 0; dt < 5; ++dt)
            av[dt] = *(const unsigned*)(phA + s5[dt] * POSTRIDE + o);
        unsigned l0a = *(const unsigned*)(phL0 + (sC    ) * POSTRIDE + o);
        unsigned l0b = *(const unsigned*)(phL0 + (sC + 1) * POSTRIDE + o);
        unsigned l1a = *(const unsigned*)(phL1 + (sC    ) * POSTRIDE + o);
        unsigned l1b = *(const unsigned*)(phL1 + (sC + 1) * POSTRIDE + o);

        float xm_l = bflo(av[2]), xm_h = bfhi(av[2]);
        float um_l = -1e30f, um_h = -1e30f;
        #pragma unroll
        for (int dt = 0; dt < 5; ++dt) {
            um_l = fmaxf(um_l, in5[dt] ? bflo(av[dt]) : 0.f);
            um_h = fmaxf(um_h, in5[dt] ? bfhi(av[dt]) : 0.f);
        }
        float l0al = bflo(l0a), l0bl = bflo(l0b), l1al = bflo(l1a), l1bl = bflo(l1b);
        float l0ah = bfhi(l0a), l0bh = bfhi(l0b), l1ah = bfhi(l1a), l1bh = bfhi(l1b);

        float rl = 2.f * xm_l + um_l + (l0bl + l0al) + qgelu(l0bl - l0al)
                                     + (l1bl + l1al) + qgelu(l1bl - l1al);
        float rh = 2.f * xm_h + um_h + (l0bh + l0ah) + qgelu(l0bh - l0ah)
                                     + (l1bh + l1ah) + qgelu(l1bh - l1ah);
        outp[(size_t)(o    ) * T_LEN] = rl;
        outp[(size_t)(o + 1) * T_LEN] = rh;
    }
}

extern "C" void kernel_launch(void* const* d_in, const int* in_sizes, int n_in,
                              void* d_out, int out_size, void* d_ws, size_t ws_size,
                              hipStream_t stream) {
    const float* x    = (const float*)d_in[0];
    const float* w    = (const float*)d_in[1];
    const float* bias = (const float*)d_in[2];
    float* out        = (float*)d_out;
    ushort_t* wold    = (ushort_t*)d_ws;                         // 212,992 B
    ushort_t* wpk     = (ushort_t*)((char*)d_ws + WS_WPK_OFF);   // 245,760 B

    hipLaunchKernelGGL(convert_w_kernel, dim3(416 + 60), dim3(256), 0, stream,
                       w, wold, wpk);
    hipLaunchKernelGGL(fused_int_kernel, dim3(N_INT), dim3(256), 0, stream,
                       x, wpk, bias, out);
    hipLaunchKernelGGL(fused_bnd_kernel, dim3(64), dim3(256), 0, stream,
                       x, wold, bias, out);
}

// Round 13
// 81.374 us; speedup vs baseline: 2.2210x; 1.0457x over previous
//
#include <hip/hip_runtime.h>
#include <hip/hip_bf16.h>

typedef __attribute__((ext_vector_type(4))) float f32x4;
typedef __attribute__((ext_vector_type(8))) short bf16x8;
typedef unsigned short ushort_t;

#define T_LEN 8192
#define N_REFL 8187              // last valid phase index (phase arrays have 8188 elems)
#define POSTRIDE 66              // u16 per phase row (boundary path only)
#define PH_U16 (80 * POSTRIDE)   // 5280 u16 per phase (boundary path only)
#define N_INT 4032               // interior blocks: 126 tiles * 2 g * 16 b
#define WS_WPK_OFF 262144        // wpk offset in ws (wold occupies first 212,992 B)

__device__ __forceinline__ ushort_t f2bf(float f) {
    union { float f; unsigned u; } a; a.f = f;
    unsigned r = a.u + 0x7FFF + ((a.u >> 16) & 1);
    return (ushort_t)(r >> 16);
}

union bf2u { __hip_bfloat162 h; unsigned u; ushort_t s[2]; };

__device__ __forceinline__ unsigned pack_bf2(float a, float b) {
    bf2u x; x.h = __float22bfloat162_rn(make_float2(a, b));  // v_cvt_pk_bf16_f32
    return x.u;
}
__device__ __forceinline__ float bflo(unsigned u) {
    union { unsigned u; float f; } x; x.u = u << 16; return x.f;
}
__device__ __forceinline__ float bfhi(unsigned u) {
    union { unsigned u; float f; } x; x.u = u & 0xffff0000u; return x.f;
}
// quick_gelu(d) = d / (1 + 2^(-2.4553418 d))  (exp2 form)
__device__ __forceinline__ float qgelu(float d) {
    return __fdividef(d, 1.f + exp2f(-2.4553418f * d));
}
__device__ __forceinline__ float rot_lane(float v, int byteIdx) {
    int r = __builtin_amdgcn_ds_bpermute(byteIdx, __builtin_bit_cast(int, v));
    return __builtin_bit_cast(float, r);
}

// ---------------------------------------------------------------------------
// Part A: wold[tap][o][c] bf16 (boundary path).
// Part B: wpk[g][wv][fid][lane][8] bf16 — per-lane MFMA fragment layout so each
//         weight-load instruction reads 1KB CONTIGUOUS.
//         fid = 3j+phase, j=(u,h) pair 0..9; phase 0=A(tap 3u),1=L0(3u+2),2=L1(3u+1).
__global__ void convert_w_kernel(const float* __restrict__ w,
                                 ushort_t* __restrict__ wold,
                                 ushort_t* __restrict__ wpk) {
    int bid = blockIdx.x;
    int tid = threadIdx.x;
    if (bid < 416) {
        int idx = bid * 256 + tid;
        if (idx >= 128 * 64 * 13) return;
        int tap = idx % 13;
        int c   = (idx / 13) & 63;
        int o   = idx / (13 * 64);
        wold[(tap * 128 + o) * 64 + c] = f2bf(w[idx]);
    } else {
        int e0   = (bid - 416) * 256 + tid;      // 0 .. 15359
        int lane = e0 & 63;
        int rest = e0 >> 6;                       // g*120 + wv*30 + fid
        int fid  = rest % 30;
        int wv   = (rest / 30) & 3;
        int g    = rest / 120;
        int j = fid / 3, phase = fid % 3;
        int u = j >> 1, h = j & 1;
        int row = lane & 15, kb = lane >> 4;
        int wo  = g * 64 + wv * 16 + row;
        int tap = 3 * u + ((phase == 0) ? 0 : (phase == 1) ? 2 : 1);
        bool zero = (phase != 0) && (u == 4);
        ushort_t* dst = wpk + (size_t)e0 * 8;
        #pragma unroll
        for (int e = 0; e < 8; ++e) {
            int c = h * 32 + kb * 8 + e;
            float v = zero ? 0.f : w[((size_t)wo * 64 + c) * 13 + tap];
            dst[e] = f2bf(v);
        }
    }
}

// ---------------------------------------------------------------------------
// Fused kernel: blocks [0, N_INT) interior (R12 path), [N_INT, N_INT+64) boundary.
__global__ __launch_bounds__(256, 4)
void fused_trconv_kernel(const float* __restrict__ x, const ushort_t* __restrict__ wpk,
                         const ushort_t* __restrict__ wold,
                         const float* __restrict__ bias, float* __restrict__ out) {
    __shared__ ushort_t smem[3 * PH_U16];   // 31,680 B (boundary); interior aliases front
    ushort_t* xs = smem;

    const int bx   = blockIdx.x;
    const int tid  = threadIdx.x;
    const int lane = tid & 63;
    const int wv   = tid >> 6;
    const int row  = lane & 15;
    const int kb   = lane >> 4;

    if (bx < N_INT) {
        // ======================= interior (R12 verbatim) =======================
        const int gb   = bx / 126;
        const int tile = 1 + (bx - gb * 126);
        const int g    = gb & 1;
        const int b    = gb >> 1;
        const int t0   = tile * 64;
        const int mbase = t0 - 8;            // in-range 56..8056

        // coalesced stage: consecutive 4 lanes read 64B contiguous of one channel
        const float* xg = x + ((size_t)b * 128 + (size_t)g * 64) * T_LEN;
        #pragma unroll
        for (int it = 0; it < 5; ++it) {
            int idx = 256 * it + tid;
            int jj  = idx & 3;
            int c   = (idx >> 2) & 63;
            int s0  = 16 * it + 4 * jj;      // rows 0..79
            float4 v = *(const float4*)(xg + (size_t)c * T_LEN + (mbase + s0));
            unsigned p01 = pack_bf2(v.x, v.y);
            unsigned p23 = pack_bf2(v.z, v.w);
            xs[(s0 + 0) * 64 + (c ^ (((s0 + 0) & 7) << 3))] = (ushort_t)(p01 & 0xffff);
            xs[(s0 + 1) * 64 + (c ^ (((s0 + 1) & 7) << 3))] = (ushort_t)(p01 >> 16);
            xs[(s0 + 2) * 64 + (c ^ (((s0 + 2) & 7) << 3))] = (ushort_t)(p23 & 0xffff);
            xs[(s0 + 3) * 64 + (c ^ (((s0 + 3) & 7) << 3))] = (ushort_t)(p23 >> 16);
        }
        if (tid < 128) {                      // tail rows 80..87
            int c  = tid >> 1;
            int s0 = 80 + 4 * (tid & 1);
            float4 v = *(const float4*)(xg + (size_t)c * T_LEN + (mbase + s0));
            unsigned p01 = pack_bf2(v.x, v.y);
            unsigned p23 = pack_bf2(v.z, v.w);
            xs[(s0 + 0) * 64 + (c ^ (((s0 + 0) & 7) << 3))] = (ushort_t)(p01 & 0xffff);
            xs[(s0 + 1) * 64 + (c ^ (((s0 + 1) & 7) << 3))] = (ushort_t)(p01 >> 16);
            xs[(s0 + 2) * 64 + (c ^ (((s0 + 2) & 7) << 3))] = (ushort_t)(p23 & 0xffff);
            xs[(s0 + 3) * 64 + (c ^ (((s0 + 3) & 7) << 3))] = (ushort_t)(p23 >> 16);
        }
        const int wo = g * 64 + wv * 16 + row;
        const float bo = bias[wo];
        const ushort_t* wp = wpk + (((size_t)(g * 4 + wv)) * 30 * 64 + lane) * 8;
        __syncthreads();

        f32x4 accA[5], accL0[5], accL1[5];
        #pragma unroll
        for (int q = 0; q < 5; ++q) {
            accA[q]  = (f32x4){0.f, 0.f, 0.f, 0.f};
            accL0[q] = (f32x4){0.f, 0.f, 0.f, 0.f};
            accL1[q] = (f32x4){0.f, 0.f, 0.f, 0.f};
        }

        #pragma unroll
        for (int j = 0; j < 10; ++j) {
            const int u = j >> 1, h = j & 1;
            bf16x8 wf0 = *(const bf16x8*)(wp + (3 * j + 0) * 512);
            bf16x8 wf1 = {}, wf2 = {};
            if (u < 4) {
                wf1 = *(const bf16x8*)(wp + (3 * j + 1) * 512);
                wf2 = *(const bf16x8*)(wp + (3 * j + 2) * 512);
            }
            #pragma unroll
            for (int q = 0; q < 5; ++q) {
                int s = 16 * q + row + u;
                const bf16x8 xa = *(const bf16x8*)(xs + s * 64 + ((h * 32 + kb * 8) ^ ((s & 7) << 3)));
                accA[q] = __builtin_amdgcn_mfma_f32_16x16x32_bf16(xa, wf0, accA[q], 0, 0, 0);
                if (u < 4) {
                    accL0[q] = __builtin_amdgcn_mfma_f32_16x16x32_bf16(xa, wf1, accL0[q], 0, 0, 0);
                    accL1[q] = __builtin_amdgcn_mfma_f32_16x16x32_bf16(xa, wf2, accL1[q], 0, 0, 0);
                }
            }
        }

        const int upIdx = ((lane + 16) & 63) << 2;
        const int dnIdx = ((lane + 48) & 63) << 2;

        float u0[6], u1[6], d2m[5], d3m[5], lu[6], lv[6];
        #pragma unroll
        for (int q = 0; q < 5; ++q) {
            u0[q]  = rot_lane(accA[q][0], upIdx);
            u1[q]  = rot_lane(accA[q][1], upIdx);
            d2m[q] = rot_lane(accA[q][2], dnIdx);
            d3m[q] = rot_lane(accA[q][3], dnIdx);
            lu[q]  = rot_lane(accL0[q][0], upIdx);
            lv[q]  = rot_lane(accL1[q][0], upIdx);
        }
        u0[5] = 0.f; u1[5] = 0.f; lu[5] = 0.f; lv[5] = 0.f;

        const bool kbLT3 = (kb < 3);
        const bool kbGT0 = (kb > 0);
        const float c7bo = 7.f * bo;
        float* outBase = out + ((size_t)(b * 128 + wo)) * T_LEN + (t0 - 6 + 4 * kb);

        #pragma unroll
        for (int q = 0; q < 5; ++q) {
            #pragma unroll
            for (int r = 0; r < 4; ++r) {
                float A0 = accA[q][r];
                float Ap1 = (r < 3) ? accA[q][r + 1] : (kbLT3 ? u0[q] : u0[q + 1]);
                float Ap2 = (r == 0) ? accA[q][2]
                          : (r == 1) ? accA[q][3]
                          : (r == 2) ? (kbLT3 ? u0[q] : u0[q + 1])
                                     : (kbLT3 ? u1[q] : u1[q + 1]);
                float Am1 = (r > 0) ? accA[q][r - 1]
                                    : (kbGT0 ? d3m[q] : (q > 0 ? d3m[q - 1] : 0.f));
                float Am2 = (r == 2) ? accA[q][0]
                          : (r == 3) ? accA[q][1]
                          : (r == 1) ? (kbGT0 ? d3m[q] : (q > 0 ? d3m[q - 1] : 0.f))
                                     : (kbGT0 ? d2m[q] : (q > 0 ? d2m[q - 1] : 0.f));
                float L0a = accL0[q][r];
                float L0b = (r < 3) ? accL0[q][r + 1] : (kbLT3 ? lu[q] : lu[q + 1]);
                float L1a = accL1[q][r];
                float L1b = (r < 3) ? accL1[q][r + 1] : (kbLT3 ? lv[q] : lv[q + 1]);

                float um = fmaxf(fmaxf(fmaxf(Am2, Am1), A0), fmaxf(Ap1, Ap2));
                float res = 2.f * A0 + um + c7bo + (L0b + L0a) + (L1b + L1a)
                          + qgelu(L0b - L0a) + qgelu(L1b - L1a);

                bool ok = true;
                if (q == 0) ok = (4 * kb + r) >= 6;
                if (q == 4) ok = (4 * kb + r) <= 5;
                if (ok) outBase[16 * q + r] = res;
            }
        }
    } else {
        // ======================= boundary (R12 bnd verbatim) =======================
        const int idx  = bx - N_INT;
        const int tile = (idx & 1) ? 127 : 0;
        const int g    = (idx >> 1) & 1;
        const int b    = idx >> 2;
        const int t0    = tile * 64;
        const int mbase = t0 - 8;

        const float* xg = x + ((size_t)b * 128 + (size_t)g * 64) * T_LEN;
        for (int cid = tid; cid < 64 * 22; cid += 256) {
            int c  = cid & 63;
            int s0 = (cid >> 6) * 4;
            int m0 = mbase + s0;
            const float* src = xg + (size_t)c * T_LEN + m0;
            float v0, v1, v2, v3;
            if (m0 >= 0 && m0 + 3 < T_LEN) {
                float4 v = *(const float4*)src;
                v0 = v.x; v1 = v.y; v2 = v.z; v3 = v.w;
            } else {
                v0 = ((unsigned)(m0 + 0) < (unsigned)T_LEN) ? src[0] : 0.f;
                v1 = ((unsigned)(m0 + 1) < (unsigned)T_LEN) ? src[1] : 0.f;
                v2 = ((unsigned)(m0 + 2) < (unsigned)T_LEN) ? src[2] : 0.f;
                v3 = ((unsigned)(m0 + 3) < (unsigned)T_LEN) ? src[3] : 0.f;
            }
            unsigned p01 = pack_bf2(v0, v1);
            unsigned p23 = pack_bf2(v2, v3);
            xs[(s0 + 0) * 64 + (c ^ (((s0 + 0) & 7) << 3))] = (ushort_t)(p01 & 0xffff);
            xs[(s0 + 1) * 64 + (c ^ (((s0 + 1) & 7) << 3))] = (ushort_t)(p01 >> 16);
            xs[(s0 + 2) * 64 + (c ^ (((s0 + 2) & 7) << 3))] = (ushort_t)(p23 & 0xffff);
            xs[(s0 + 3) * 64 + (c ^ (((s0 + 3) & 7) << 3))] = (ushort_t)(p23 >> 16);
        }
        __syncthreads();

        f32x4 accA[5], accL0[5], accL1[5];
        #pragma unroll
        for (int q = 0; q < 5; ++q) {
            accA[q]  = (f32x4){0.f, 0.f, 0.f, 0.f};
            accL0[q] = (f32x4){0.f, 0.f, 0.f, 0.f};
            accL1[q] = (f32x4){0.f, 0.f, 0.f, 0.f};
        }
        const int wo = g * 64 + wv * 16 + row;

        #pragma unroll
        for (int u = 0; u < 5; ++u) {
            #pragma unroll
            for (int h = 0; h < 2; ++h) {
                bf16x8 wf0 = *(const bf16x8*)(wold + ((3 * u + 0) * 128 + wo) * 64 + h * 32 + kb * 8);
                bf16x8 wf1 = {}, wf2 = {};
                if (u < 4) {
                    wf1 = *(const bf16x8*)(wold + ((3 * u + 2) * 128 + wo) * 64 + h * 32 + kb * 8);
                    wf2 = *(const bf16x8*)(wold + ((3 * u + 1) * 128 + wo) * 64 + h * 32 + kb * 8);
                }
                #pragma unroll
                for (int q = 0; q < 5; ++q) {
                    int s = 16 * q + row + u;
                    const bf16x8 xa = *(const bf16x8*)(xs + s * 64 + ((h * 32 + kb * 8) ^ ((s & 7) << 3)));
                    accA[q] = __builtin_amdgcn_mfma_f32_16x16x32_bf16(xa, wf0, accA[q], 0, 0, 0);
                    if (u < 4) {
                        accL0[q] = __builtin_amdgcn_mfma_f32_16x16x32_bf16(xa, wf1, accL0[q], 0, 0, 0);
                        accL1[q] = __builtin_amdgcn_mfma_f32_16x16x32_bf16(xa, wf2, accL1[q], 0, 0, 0);
                    }
                }
            }
        }
        const float bo = bias[wo];
        __syncthreads();

        #pragma unroll
        for (int q = 0; q < 5; ++q) {
            #pragma unroll
            for (int p = 0; p < 3; ++p) {
                const f32x4& a = (p == 0) ? accA[q] : (p == 1) ? accL0[q] : accL1[q];
                unsigned pa = pack_bf2(a[0] + bo, a[1] + bo);
                unsigned pb = pack_bf2(a[2] + bo, a[3] + bo);
                int base = p * PH_U16 + (16 * q + kb * 4) * POSTRIDE + wv * 16 + row;
                smem[base + 0 * POSTRIDE] = (ushort_t)(pa & 0xffff);
                smem[base + 1 * POSTRIDE] = (ushort_t)(pa >> 16);
                smem[base + 2 * POSTRIDE] = (ushort_t)(pb & 0xffff);
                smem[base + 3 * POSTRIDE] = (ushort_t)(pb >> 16);
            }
        }
        __syncthreads();

        const int tl = tid & 63;
        const int wq = tid >> 6;
        const int t  = t0 + tl;
        const ushort_t* phA  = smem;
        const ushort_t* phL0 = smem + PH_U16;
        const ushort_t* phL1 = smem + 2 * PH_U16;
        float* outp = out + ((size_t)b * 128 + (size_t)g * 64) * T_LEN + t;

        int  s5[5];
        bool in5[5];
        #pragma unroll
        for (int dt = 0; dt < 5; ++dt) {
            int tp = t + dt - 2;
            in5[dt] = ((unsigned)tp < (unsigned)T_LEN);
            int ix = tp - 2;
            ix = (ix < 0) ? -ix : ix;
            ix = (ix > N_REFL) ? (2 * N_REFL - ix) : ix;
            s5[dt] = ix - mbase;
        }
        const int sC = s5[2];
        for (int i = 0; i < 8; ++i) {
            int o = 2 * wq + 8 * i;
            unsigned av[5];
            #pragma unroll
            for (int dt = 0; dt < 5; ++dt)
                av[dt] = *(const unsigned*)(phA + s5[dt] * POSTRIDE + o);
            unsigned l0a = *(const unsigned*)(phL0 + (sC    ) * POSTRIDE + o);
            unsigned l0b = *(const unsigned*)(phL0 + (sC + 1) * POSTRIDE + o);
            unsigned l1a = *(const unsigned*)(phL1 + (sC    ) * POSTRIDE + o);
            unsigned l1b = *(const unsigned*)(phL1 + (sC + 1) * POSTRIDE + o);

            float xm_l = bflo(av[2]), xm_h = bfhi(av[2]);
            float um_l = -1e30f, um_h = -1e30f;
            #pragma unroll
            for (int dt = 0; dt < 5; ++dt) {
                um_l = fmaxf(um_l, in5[dt] ? bflo(av[dt]) : 0.f);
                um_h = fmaxf(um_h, in5[dt] ? bfhi(av[dt]) : 0.f);
            }
            float l0al = bflo(l0a), l0bl = bflo(l0b), l1al = bflo(l1a), l1bl = bflo(l1b);
            float l0ah = bfhi(l0a), l0bh = bfhi(l0b), l1ah = bfhi(l1a), l1bh = bfhi(l1b);

            float rl = 2.f * xm_l + um_l + (l0bl + l0al) + qgelu(l0bl - l0al)
                                         + (l1bl + l1al) + qgelu(l1bl - l1al);
            float rh = 2.f * xm_h + um_h + (l0bh + l0ah) + qgelu(l0bh - l0ah)
                                         + (l1bh + l1ah) + qgelu(l1bh - l1ah);
            outp[(size_t)(o    ) * T_LEN] = rl;
            outp[(size_t)(o + 1) * T_LEN] = rh;
        }
    }
}

extern "C" void kernel_launch(void* const* d_in, const int* in_sizes, int n_in,
                              void* d_out, int out_size, void* d_ws, size_t ws_size,
                              hipStream_t stream) {
    const float* x    = (const float*)d_in[0];
    const float* w    = (const float*)d_in[1];
    const float* bias = (const float*)d_in[2];
    float* out        = (float*)d_out;
    ushort_t* wold    = (ushort_t*)d_ws;                         // 212,992 B
    ushort_t* wpk     = (ushort_t*)((char*)d_ws + WS_WPK_OFF);   // 245,760 B

    hipLaunchKernelGGL(convert_w_kernel, dim3(416 + 60), dim3(256), 0, stream,
                       w, wold, wpk);
    hipLaunchKernelGGL(fused_trconv_kernel, dim3(N_INT + 64), dim3(256), 0, stream,
                       x, wpk, wold, bias, out);
}

// Round 14
// 77.836 us; speedup vs baseline: 2.3219x; 1.0454x over previous
//
#include <hip/hip_runtime.h>
#include <hip/hip_bf16.h>

typedef __attribute__((ext_vector_type(4))) float f32x4;
typedef __attribute__((ext_vector_type(8))) short bf16x8;
typedef unsigned short ushort_t;

#define T_LEN 8192
#define N_REFL 8187              // last valid phase index (phase arrays have 8188 elems)
#define POSTRIDE 66              // u16 per phase row (boundary path only)
#define PH_U16 (80 * POSTRIDE)   // 5280 u16 per phase (boundary path only)
#define N_INT 4032               // interior blocks: 126 tiles * 2 g * 16 b  (= 8 * 504)
#define WS_WPK_OFF 262144        // wpk offset in ws (wold occupies first 212,992 B)

__device__ __forceinline__ ushort_t f2bf(float f) {
    union { float f; unsigned u; } a; a.f = f;
    unsigned r = a.u + 0x7FFF + ((a.u >> 16) & 1);
    return (ushort_t)(r >> 16);
}

union bf2u { __hip_bfloat162 h; unsigned u; ushort_t s[2]; };

__device__ __forceinline__ unsigned pack_bf2(float a, float b) {
    bf2u x; x.h = __float22bfloat162_rn(make_float2(a, b));  // v_cvt_pk_bf16_f32
    return x.u;
}
__device__ __forceinline__ float bflo(unsigned u) {
    union { unsigned u; float f; } x; x.u = u << 16; return x.f;
}
__device__ __forceinline__ float bfhi(unsigned u) {
    union { unsigned u; float f; } x; x.u = u & 0xffff0000u; return x.f;
}
// quick_gelu(d) = d / (1 + 2^(-2.4553418 d))  (exp2 form)
__device__ __forceinline__ float qgelu(float d) {
    return __fdividef(d, 1.f + exp2f(-2.4553418f * d));
}
__device__ __forceinline__ float rot_lane(float v, int byteIdx) {
    int r = __builtin_amdgcn_ds_bpermute(byteIdx, __builtin_bit_cast(int, v));
    return __builtin_bit_cast(float, r);
}

// ---------------------------------------------------------------------------
// Part A: wold[tap][o][c] bf16 (boundary path).
// Part B: wpk[g][wv][fid][lane][8] bf16 — per-lane MFMA fragment layout so each
//         weight-load instruction reads 1KB CONTIGUOUS.
//         fid = 3j+phase, j=(u,h) pair 0..9; phase 0=A(tap 3u),1=L0(3u+2),2=L1(3u+1).
__global__ void convert_w_kernel(const float* __restrict__ w,
                                 ushort_t* __restrict__ wold,
                                 ushort_t* __restrict__ wpk) {
    int bid = blockIdx.x;
    int tid = threadIdx.x;
    if (bid < 416) {
        int idx = bid * 256 + tid;
        if (idx >= 128 * 64 * 13) return;
        int tap = idx % 13;
        int c   = (idx / 13) & 63;
        int o   = idx / (13 * 64);
        wold[(tap * 128 + o) * 64 + c] = f2bf(w[idx]);
    } else {
        int e0   = (bid - 416) * 256 + tid;      // 0 .. 15359
        int lane = e0 & 63;
        int rest = e0 >> 6;                       // g*120 + wv*30 + fid
        int fid  = rest % 30;
        int wv   = (rest / 30) & 3;
        int g    = rest / 120;
        int j = fid / 3, phase = fid % 3;
        int u = j >> 1, h = j & 1;
        int row = lane & 15, kb = lane >> 4;
        int wo  = g * 64 + wv * 16 + row;
        int tap = 3 * u + ((phase == 0) ? 0 : (phase == 1) ? 2 : 1);
        bool zero = (phase != 0) && (u == 4);
        ushort_t* dst = wpk + (size_t)e0 * 8;
        #pragma unroll
        for (int e = 0; e < 8; ++e) {
            int c = h * 32 + kb * 8 + e;
            float v = zero ? 0.f : w[((size_t)wo * 64 + c) * 13 + tap];
            dst[e] = f2bf(v);
        }
    }
}

// ---------------------------------------------------------------------------
// Fused kernel: blocks [0, N_INT) interior (XCD-swizzled), [N_INT, N_INT+64) boundary.
__global__ __launch_bounds__(256, 4)
void fused_trconv_kernel(const float* __restrict__ x, const ushort_t* __restrict__ wpk,
                         const ushort_t* __restrict__ wold,
                         const float* __restrict__ bias, float* __restrict__ out) {
    __shared__ ushort_t smem[3 * PH_U16];   // 31,680 B (boundary); interior aliases front
    ushort_t* xs = smem;

    const int bxl  = blockIdx.x;
    const int tid  = threadIdx.x;
    const int lane = tid & 63;
    const int wv   = tid >> 6;
    const int row  = lane & 15;
    const int kb   = lane >> 4;

    if (bxl < N_INT) {
        // ======================= interior (R13 path + XCD swizzle) =======================
        // Bijective XCD swizzle: 4032 = 8*504; consecutive logical tiles share one XCD's L2,
        // so 24-row stage halos and packed-weight lines become L2 hits.
        const int bx   = (bxl & 7) * 504 + (bxl >> 3);
        const int gb   = bx / 126;
        const int tile = 1 + (bx - gb * 126);
        const int g    = gb & 1;
        const int b    = gb >> 1;
        const int t0   = tile * 64;
        const int mbase = t0 - 8;            // in-range 56..8056

        // coalesced stage: consecutive 4 lanes read 64B contiguous of one channel
        const float* xg = x + ((size_t)b * 128 + (size_t)g * 64) * T_LEN;
        #pragma unroll
        for (int it = 0; it < 5; ++it) {
            int idx = 256 * it + tid;
            int jj  = idx & 3;
            int c   = (idx >> 2) & 63;
            int s0  = 16 * it + 4 * jj;      // rows 0..79
            float4 v = *(const float4*)(xg + (size_t)c * T_LEN + (mbase + s0));
            unsigned p01 = pack_bf2(v.x, v.y);
            unsigned p23 = pack_bf2(v.z, v.w);
            xs[(s0 + 0) * 64 + (c ^ (((s0 + 0) & 7) << 3))] = (ushort_t)(p01 & 0xffff);
            xs[(s0 + 1) * 64 + (c ^ (((s0 + 1) & 7) << 3))] = (ushort_t)(p01 >> 16);
            xs[(s0 + 2) * 64 + (c ^ (((s0 + 2) & 7) << 3))] = (ushort_t)(p23 & 0xffff);
            xs[(s0 + 3) * 64 + (c ^ (((s0 + 3) & 7) << 3))] = (ushort_t)(p23 >> 16);
        }
        if (tid < 128) {                      // tail rows 80..87
            int c  = tid >> 1;
            int s0 = 80 + 4 * (tid & 1);
            float4 v = *(const float4*)(xg + (size_t)c * T_LEN + (mbase + s0));
            unsigned p01 = pack_bf2(v.x, v.y);
            unsigned p23 = pack_bf2(v.z, v.w);
            xs[(s0 + 0) * 64 + (c ^ (((s0 + 0) & 7) << 3))] = (ushort_t)(p01 & 0xffff);
            xs[(s0 + 1) * 64 + (c ^ (((s0 + 1) & 7) << 3))] = (ushort_t)(p01 >> 16);
            xs[(s0 + 2) * 64 + (c ^ (((s0 + 2) & 7) << 3))] = (ushort_t)(p23 & 0xffff);
            xs[(s0 + 3) * 64 + (c ^ (((s0 + 3) & 7) << 3))] = (ushort_t)(p23 >> 16);
        }
        const int wo = g * 64 + wv * 16 + row;
        const float bo = bias[wo];
        const ushort_t* wp = wpk + (((size_t)(g * 4 + wv)) * 30 * 64 + lane) * 8;
        __syncthreads();

        f32x4 accA[5], accL0[5], accL1[5];
        #pragma unroll
        for (int q = 0; q < 5; ++q) {
            accA[q]  = (f32x4){0.f, 0.f, 0.f, 0.f};
            accL0[q] = (f32x4){0.f, 0.f, 0.f, 0.f};
            accL1[q] = (f32x4){0.f, 0.f, 0.f, 0.f};
        }

        #pragma unroll
        for (int j = 0; j < 10; ++j) {
            const int u = j >> 1, h = j & 1;
            bf16x8 wf0 = *(const bf16x8*)(wp + (3 * j + 0) * 512);
            bf16x8 wf1 = {}, wf2 = {};
            if (u < 4) {
                wf1 = *(const bf16x8*)(wp + (3 * j + 1) * 512);
                wf2 = *(const bf16x8*)(wp + (3 * j + 2) * 512);
            }
            #pragma unroll
            for (int q = 0; q < 5; ++q) {
                int s = 16 * q + row + u;
                const bf16x8 xa = *(const bf16x8*)(xs + s * 64 + ((h * 32 + kb * 8) ^ ((s & 7) << 3)));
                accA[q] = __builtin_amdgcn_mfma_f32_16x16x32_bf16(xa, wf0, accA[q], 0, 0, 0);
                if (u < 4) {
                    accL0[q] = __builtin_amdgcn_mfma_f32_16x16x32_bf16(xa, wf1, accL0[q], 0, 0, 0);
                    accL1[q] = __builtin_amdgcn_mfma_f32_16x16x32_bf16(xa, wf2, accL1[q], 0, 0, 0);
                }
            }
        }

        const int upIdx = ((lane + 16) & 63) << 2;
        const int dnIdx = ((lane + 48) & 63) << 2;

        float u0[6], u1[6], d2m[5], d3m[5], lu[6], lv[6];
        #pragma unroll
        for (int q = 0; q < 5; ++q) {
            u0[q]  = rot_lane(accA[q][0], upIdx);
            u1[q]  = rot_lane(accA[q][1], upIdx);
            d2m[q] = rot_lane(accA[q][2], dnIdx);
            d3m[q] = rot_lane(accA[q][3], dnIdx);
            lu[q]  = rot_lane(accL0[q][0], upIdx);
            lv[q]  = rot_lane(accL1[q][0], upIdx);
        }
        u0[5] = 0.f; u1[5] = 0.f; lu[5] = 0.f; lv[5] = 0.f;

        const bool kbLT3 = (kb < 3);
        const bool kbGT0 = (kb > 0);
        const float c7bo = 7.f * bo;
        float* outBase = out + ((size_t)(b * 128 + wo)) * T_LEN + (t0 - 6 + 4 * kb);

        #pragma unroll
        for (int q = 0; q < 5; ++q) {
            #pragma unroll
            for (int r = 0; r < 4; ++r) {
                float A0 = accA[q][r];
                float Ap1 = (r < 3) ? accA[q][r + 1] : (kbLT3 ? u0[q] : u0[q + 1]);
                float Ap2 = (r == 0) ? accA[q][2]
                          : (r == 1) ? accA[q][3]
                          : (r == 2) ? (kbLT3 ? u0[q] : u0[q + 1])
                                     : (kbLT3 ? u1[q] : u1[q + 1]);
                float Am1 = (r > 0) ? accA[q][r - 1]
                                    : (kbGT0 ? d3m[q] : (q > 0 ? d3m[q - 1] : 0.f));
                float Am2 = (r == 2) ? accA[q][0]
                          : (r == 3) ? accA[q][1]
                          : (r == 1) ? (kbGT0 ? d3m[q] : (q > 0 ? d3m[q - 1] : 0.f))
                                     : (kbGT0 ? d2m[q] : (q > 0 ? d2m[q - 1] : 0.f));
                float L0a = accL0[q][r];
                float L0b = (r < 3) ? accL0[q][r + 1] : (kbLT3 ? lu[q] : lu[q + 1]);
                float L1a = accL1[q][r];
                float L1b = (r < 3) ? accL1[q][r + 1] : (kbLT3 ? lv[q] : lv[q + 1]);

                float um = fmaxf(fmaxf(fmaxf(Am2, Am1), A0), fmaxf(Ap1, Ap2));
                float res = 2.f * A0 + um + c7bo + (L0b + L0a) + (L1b + L1a)
                          + qgelu(L0b - L0a) + qgelu(L1b - L1a);

                bool ok = true;
                if (q == 0) ok = (4 * kb + r) >= 6;
                if (q == 4) ok = (4 * kb + r) <= 5;
                if (ok) outBase[16 * q + r] = res;
            }
        }
    } else {
        // ======================= boundary (R13 verbatim) =======================
        const int idx  = bxl - N_INT;
        const int tile = (idx & 1) ? 127 : 0;
        const int g    = (idx >> 1) & 1;
        const int b    = idx >> 2;
        const int t0    = tile * 64;
        const int mbase = t0 - 8;

        const float* xg = x + ((size_t)b * 128 + (size_t)g * 64) * T_LEN;
        for (int cid = tid; cid < 64 * 22; cid += 256) {
            int c  = cid & 63;
            int s0 = (cid >> 6) * 4;
            int m0 = mbase + s0;
            const float* src = xg + (size_t)c * T_LEN + m0;
            float v0, v1, v2, v3;
            if (m0 >= 0 && m0 + 3 < T_LEN) {
                float4 v = *(const float4*)src;
                v0 = v.x; v1 = v.y; v2 = v.z; v3 = v.w;
            } else {
                v0 = ((unsigned)(m0 + 0) < (unsigned)T_LEN) ? src[0] : 0.f;
                v1 = ((unsigned)(m0 + 1) < (unsigned)T_LEN) ? src[1] : 0.f;
                v2 = ((unsigned)(m0 + 2) < (unsigned)T_LEN) ? src[2] : 0.f;
                v3 = ((unsigned)(m0 + 3) < (unsigned)T_LEN) ? src[3] : 0.f;
            }
            unsigned p01 = pack_bf2(v0, v1);
            unsigned p23 = pack_bf2(v2, v3);
            xs[(s0 + 0) * 64 + (c ^ (((s0 + 0) & 7) << 3))] = (ushort_t)(p01 & 0xffff);
            xs[(s0 + 1) * 64 + (c ^ (((s0 + 1) & 7) << 3))] = (ushort_t)(p01 >> 16);
            xs[(s0 + 2) * 64 + (c ^ (((s0 + 2) & 7) << 3))] = (ushort_t)(p23 & 0xffff);
            xs[(s0 + 3) * 64 + (c ^ (((s0 + 3) & 7) << 3))] = (ushort_t)(p23 >> 16);
        }
        __syncthreads();

        f32x4 accA[5], accL0[5], accL1[5];
        #pragma unroll
        for (int q = 0; q < 5; ++q) {
            accA[q]  = (f32x4){0.f, 0.f, 0.f, 0.f};
            accL0[q] = (f32x4){0.f, 0.f, 0.f, 0.f};
            accL1[q] = (f32x4){0.f, 0.f, 0.f, 0.f};
        }
        const int wo = g * 64 + wv * 16 + row;

        #pragma unroll
        for (int u = 0; u < 5; ++u) {
            #pragma unroll
            for (int h = 0; h < 2; ++h) {
                bf16x8 wf0 = *(const bf16x8*)(wold + ((3 * u + 0) * 128 + wo) * 64 + h * 32 + kb * 8);
                bf16x8 wf1 = {}, wf2 = {};
                if (u < 4) {
                    wf1 = *(const bf16x8*)(wold + ((3 * u + 2) * 128 + wo) * 64 + h * 32 + kb * 8);
                    wf2 = *(const bf16x8*)(wold + ((3 * u + 1) * 128 + wo) * 64 + h * 32 + kb * 8);
                }
                #pragma unroll
                for (int q = 0; q < 5; ++q) {
                    int s = 16 * q + row + u;
                    const bf16x8 xa = *(const bf16x8*)(xs + s * 64 + ((h * 32 + kb * 8) ^ ((s & 7) << 3)));
                    accA[q] = __builtin_amdgcn_mfma_f32_16x16x32_bf16(xa, wf0, accA[q], 0, 0, 0);
                    if (u < 4) {
                        accL0[q] = __builtin_amdgcn_mfma_f32_16x16x32_bf16(xa, wf1, accL0[q], 0, 0, 0);
                        accL1[q] = __builtin_amdgcn_mfma_f32_16x16x32_bf16(xa, wf2, accL1[q], 0, 0, 0);
                    }
                }
            }
        }
        const float bo = bias[wo];
        __syncthreads();

        #pragma unroll
        for (int q = 0; q < 5; ++q) {
            #pragma unroll
            for (int p = 0; p < 3; ++p) {
                const f32x4& a = (p == 0) ? accA[q] : (p == 1) ? accL0[q] : accL1[q];
                unsigned pa = pack_bf2(a[0] + bo, a[1] + bo);
                unsigned pb = pack_bf2(a[2] + bo, a[3] + bo);
                int base = p * PH_U16 + (16 * q + kb * 4) * POSTRIDE + wv * 16 + row;
                smem[base + 0 * POSTRIDE] = (ushort_t)(pa & 0xffff);
                smem[base + 1 * POSTRIDE] = (ushort_t)(pa >> 16);
                smem[base + 2 * POSTRIDE] = (ushort_t)(pb & 0xffff);
                smem[base + 3 * POSTRIDE] = (ushort_t)(pb >> 16);
            }
        }
        __syncthreads();

        const int tl = tid & 63;
        const int wq = tid >> 6;
        const int t  = t0 + tl;
        const ushort_t* phA  = smem;
        const ushort_t* phL0 = smem + PH_U16;
        const ushort_t* phL1 = smem + 2 * PH_U16;
        float* outp = out + ((size_t)b * 128 + (size_t)g * 64) * T_LEN + t;

        int  s5[5];
        bool in5[5];
        #pragma unroll
        for (int dt = 0; dt < 5; ++dt) {
            int tp = t + dt - 2;
            in5[dt] = ((unsigned)tp < (unsigned)T_LEN);
            int ix = tp - 2;
            ix = (ix < 0) ? -ix : ix;
            ix = (ix > N_REFL) ? (2 * N_REFL - ix) : ix;
            s5[dt] = ix - mbase;
        }
        const int sC = s5[2];
        for (int i = 0; i < 8; ++i) {
            int o = 2 * wq + 8 * i;
            unsigned av[5];
            #pragma unroll
            for (int dt = 0; dt < 5; ++dt)
                av[dt] = *(const unsigned*)(phA + s5[dt] * POSTRIDE + o);
            unsigned l0a = *(const unsigned*)(phL0 + (sC    ) * POSTRIDE + o);
            unsigned l0b = *(const unsigned*)(phL0 + (sC + 1) * POSTRIDE + o);
            unsigned l1a = *(const unsigned*)(phL1 + (sC    ) * POSTRIDE + o);
            unsigned l1b = *(const unsigned*)(phL1 + (sC + 1) * POSTRIDE + o);

            float xm_l = bflo(av[2]), xm_h = bfhi(av[2]);
            float um_l = -1e30f, um_h = -1e30f;
            #pragma unroll
            for (int dt = 0; dt < 5; ++dt) {
                um_l = fmaxf(um_l, in5[dt] ? bflo(av[dt]) : 0.f);
                um_h = fmaxf(um_h, in5[dt] ? bfhi(av[dt]) : 0.f);
            }
            float l0al = bflo(l0a), l0bl = bflo(l0b), l1al = bflo(l1a), l1bl = bflo(l1b);
            float l0ah = bfhi(l0a), l0bh = bfhi(l0b), l1ah = bfhi(l1a), l1bh = bfhi(l1b);

            float rl = 2.f * xm_l + um_l + (l0bl + l0al) + qgelu(l0bl - l0al)
                                         + (l1bl + l1al) + qgelu(l1bl - l1al);
            float rh = 2.f * xm_h + um_h + (l0bh + l0ah) + qgelu(l0bh - l0ah)
                                         + (l1bh + l1ah) + qgelu(l1bh - l1ah);
            outp[(size_t)(o    ) * T_LEN] = rl;
            outp[(size_t)(o + 1) * T_LEN] = rh;
        }
    }
}

extern "C" void kernel_launch(void* const* d_in, const int* in_sizes, int n_in,
                              void* d_out, int out_size, void* d_ws, size_t ws_size,
                              hipStream_t stream) {
    const float* x    = (const float*)d_in[0];
    const float* w    = (const float*)d_in[1];
    const float* bias = (const float*)d_in[2];
    float* out        = (float*)d_out;
    ushort_t* wold    = (ushort_t*)d_ws;                         // 212,992 B
    ushort_t* wpk     = (ushort_t*)((char*)d_ws + WS_WPK_OFF);   // 245,760 B

    hipLaunchKernelGGL(convert_w_kernel, dim3(416 + 60), dim3(256), 0, stream,
                       w, wold, wpk);
    hipLaunchKernelGGL(fused_trconv_kernel, dim3(N_INT + 64), dim3(256), 0, stream,
                       x, wpk, wold, bias, out);
}